// Round 2
// baseline (433.644 us; speedup 1.0000x reference)
//
#include <hip/hip_runtime.h>

#define SEQ    1024
#define NT     128     // num tags
#define NBATCH 256
#define THREADS 256    // 4 waves; tid = j*2 + q, j=tag, q=i-half

typedef float v2f __attribute__((ext_vector_type(2)));

// One block per batch element, scaled forward algorithm with exact pow-2
// rescaling. Thread (j,q) owns output tag j and sums predecessor half q.
__global__ __launch_bounds__(THREADS) void crf_fwd(
    const float* __restrict__ emissions,   // [B, SEQ, NT]
    const float* __restrict__ transitions, // [NT, NT]
    const int*   __restrict__ tags,        // [B, SEQ]
    const float* __restrict__ mask,        // [B, SEQ]
    float* __restrict__ out)               // [1]
{
    const int b    = blockIdx.x;
    const int tid  = threadIdx.x;
    const int j    = tid >> 1;    // 0..127 output tag
    const int q    = tid & 1;     // 0..1 predecessor half
    const int lane = tid & 63;

    __shared__ __align__(16) float g_lds[2][NT];
    __shared__ float red[THREADS / 64];

    const float* emb = emissions + (size_t)b * SEQ * NT;
    const float* mkb = mask      + (size_t)b * SEQ;

    // exp(transitions) column j, rows q*64 .. q*64+63, as 32 float2 in regs
    v2f colT[32];
#pragma unroll
    for (int k = 0; k < 32; ++k) {
        int i = q * 64 + 2 * k;
        colT[k].x = __expf(transitions[(i    ) * NT + j]);
        colT[k].y = __expf(transitions[(i + 1) * NT + j]);
    }

    // init: gamma_0 = exp(emissions[b,0,:])
    if (q == 0) g_lds[0][j] = __expf(emb[j]);
    __syncthreads();

    int kSum = 0;   // sum of pow-2 rescale exponents (all threads track it)
    int p    = 0;   // parity: current gamma in g_lds[p]

    // pipeline: 2 steps per group; thread (j,q) holds emission for step t0+q.
    float Ecur, M0, M1;
    Ecur = emb[(1 + q) * NT + j];
    M0   = mkb[1];
    M1   = mkb[2];

    for (int t0 = 1; t0 < SEQ; t0 += 2) {
        // prefetch next group (clamped)
        int tn = t0 + 2 + q; if (tn > SEQ - 1) tn = SEQ - 1;
        float En  = emb[tn * NT + j];
        int   tm0 = t0 + 2 < SEQ ? t0 + 2 : SEQ - 1;
        int   tm1 = t0 + 3 < SEQ ? t0 + 3 : SEQ - 1;
        float Mn0 = mkb[tm0];
        float Mn1 = mkb[tm1];

#pragma unroll
        for (int dq = 0; dq < 2; ++dq) {
            int t = t0 + dq;
            if (t < SEQ) {
                float mt = dq ? M1 : M0;   // block-uniform
                if (mt != 0.0f) {
                    // broadcast read of the scale source first (latency hides
                    // under the FMA stream)
                    float c0 = g_lds[p][0];
                    const float* gp = &g_lds[p][q * 64];
                    v2f s0 = {0.f, 0.f}, s1 = {0.f, 0.f};
                    v2f s2 = {0.f, 0.f}, s3 = {0.f, 0.f};
#pragma unroll
                    for (int c = 0; c < 8; ++c) {
                        float4 ga = *(const float4*)(gp + c * 8);
                        float4 gb = *(const float4*)(gp + c * 8 + 4);
                        v2f a0 = {ga.x, ga.y}, a1 = {ga.z, ga.w};
                        v2f b0 = {gb.x, gb.y}, b1 = {gb.z, gb.w};
                        s0 = __builtin_elementwise_fma(colT[4 * c + 0], a0, s0);
                        s1 = __builtin_elementwise_fma(colT[4 * c + 1], a1, s1);
                        s2 = __builtin_elementwise_fma(colT[4 * c + 2], b0, s2);
                        s3 = __builtin_elementwise_fma(colT[4 * c + 3], b1, s3);
                    }
                    float s = ((s0.x + s0.y) + (s1.x + s1.y))
                            + ((s2.x + s2.y) + (s3.x + s3.y));
                    // combine the two i-halves (partner = adjacent lane)
                    s += __shfl_xor(s, 1, 64);

                    // exact pow-2 rescale from exponent of c0 (= g[0])
                    int k = (int)(__float_as_uint(c0) >> 23) - 127;
                    float rc = __uint_as_float((uint32_t)(127 - k) << 23);
                    kSum += k;

                    // only the parity-matching thread writes (it holds E[t][j])
                    if (q == dq) {
                        float gamma = s * rc * __expf(Ecur);
                        g_lds[p ^ 1][j] = gamma;
                    }
                    p ^= 1;
                }
                __syncthreads();
            }
        }
        Ecur = En; M0 = Mn0; M1 = Mn1;
    }

    // logZ = log(sum_j gamma[j]) + kSum*ln2
    float v = (tid < NT) ? g_lds[p][tid] : 0.0f;
#pragma unroll
    for (int o = 32; o > 0; o >>= 1) v += __shfl_down(v, o, 64);
    if (lane == 0) red[tid >> 6] = v;
    __syncthreads();
    float sumG = 0.0f;
    if (tid == 0) {
#pragma unroll
        for (int k = 0; k < THREADS / 64; ++k) sumG += red[k];
    }
    __syncthreads();   // protect red[] before reuse

    // score_b = sum_t emissions[b,t,tag_t]*mask_t
    //         + sum_{t>=1} T[tag_{t-1}, tag_t]*mask_t
    const int* tgb = tags + (size_t)b * SEQ;
    float sc = 0.0f;
    for (int t = tid; t < SEQ; t += THREADS) {
        int   tg = tgb[t];
        float mt = mkb[t];
        sc += emb[t * NT + tg] * mt;
        if (t >= 1) {
            int tgp = tgb[t - 1];
            sc += transitions[tgp * NT + tg] * mt;
        }
    }
#pragma unroll
    for (int o = 32; o > 0; o >>= 1) sc += __shfl_down(sc, o, 64);
    if (lane == 0) red[tid >> 6] = sc;
    __syncthreads();

    if (tid == 0) {
        float score = 0.0f;
#pragma unroll
        for (int k = 0; k < THREADS / 64; ++k) score += red[k];
        float logZ = __logf(sumG) + (float)kSum * 0.69314718055994531f;
        atomicAdd(out, (logZ - score) * (1.0f / NBATCH));
    }
}

extern "C" void kernel_launch(void* const* d_in, const int* in_sizes, int n_in,
                              void* d_out, int out_size, void* d_ws, size_t ws_size,
                              hipStream_t stream) {
    const float* emissions   = (const float*)d_in[0];
    const float* transitions = (const float*)d_in[1];
    const int*   tags        = (const int*)d_in[2];
    const float* mask        = (const float*)d_in[3];
    float*       out         = (float*)d_out;

    hipMemsetAsync(out, 0, sizeof(float), stream);
    crf_fwd<<<NBATCH, THREADS, 0, stream>>>(emissions, transitions, tags, mask, out);
}